// Round 5
// baseline (141.405 us; speedup 1.0000x reference)
//
#include <hip/hip_runtime.h>
#include <hip/hip_bf16.h>
#include <math.h>

// Problem constants (B=2, C=256, H=W=64, Co=256, 3x3, stride1, pad1)
#define BB 2
#define CC 256
#define HH 64
#define WW 64
#define COo 256
#define HWs 4096
#define K2 9
#define CK 2304   // C*9

typedef __attribute__((ext_vector_type(4))) float floatx4;
typedef __attribute__((ext_vector_type(8))) short shortx8;   // 8 bf16

// ---- workspace layout (float units) ----
#define O_OFF   0          // final offset  B*18*4096 = 147456 f
#define O_MASK  147456     // final modulator B*9*4096 = 73728 f
#define O_WBF   221184     // reg_w bf16 [co][k*256+c] = 294912 f  (tap-major)
#define O_WPK   516096     // convA weights [g2][kc8][tap9][nf2][lane][8] = 73728 f
#define O_XT    10027008   // x NHWC bf16 [b][y][x][c] = 1048576 f
#define O_RT    11075584   // residual NHWC bf16 = 1048576 f

__device__ __forceinline__ void gll16(const __hip_bfloat16* g, __hip_bfloat16* l) {
    __builtin_amdgcn_global_load_lds(
        (const __attribute__((address_space(1))) unsigned int*)g,
        (__attribute__((address_space(3))) unsigned int*)l, 16, 0, 0);
}

__device__ __forceinline__ short f2bf(float v) {
    __hip_bfloat16 h = __float2bfloat16(v);
    return *reinterpret_cast<short*>(&h);
}

__device__ __forceinline__ float bf2f(short s) {
    unsigned u = ((unsigned)(unsigned short)s) << 16;
    return __builtin_bit_cast(float, u);
}

// ---------------------------------------------------------------------------
// K0: FUSED prep = transpose (blocks 0..2047) + weight pack (blocks 2048+).
// Wbf tap-major: Wbf[co*2304 + k*256 + c] = reg_w[co][c][k]. (verbatim R14)
// ---------------------------------------------------------------------------
__global__ __launch_bounds__(256) void prep_kernel(
    const float* __restrict__ x,
    const float* __restrict__ residual,
    const float* __restrict__ reg_w,
    const float* __restrict__ off_w,
    const float* __restrict__ mod_w,
    __hip_bfloat16* __restrict__ xT,
    __hip_bfloat16* __restrict__ resT,
    __hip_bfloat16* __restrict__ Wbf,
    __hip_bfloat16* __restrict__ Wpk)
{
    int blk = blockIdx.x;
    int t = threadIdx.x;
    if (blk < 2048) {
        int sel = blk >> 10;             // 0 = x, 1 = residual
        int bk  = blk & 1023;            // ((b*64 + y)*8 + oc)
        int oc = bk & 7;
        int y  = (bk >> 3) & 63;
        int b  = bk >> 9;
        int wo = t & 63;
        int cg = t >> 6;
        int c0 = oc * 32 + cg * 8;
        const float* src = (sel ? residual : x)
                           + ((size_t)(b * CC + c0) * HH + y) * WW + wo;
        shortx8 pk;
#pragma unroll
        for (int j = 0; j < 8; ++j) pk[j] = f2bf(src[(size_t)j * HWs]);
        __hip_bfloat16* dst = sel ? resT : xT;
        *(shortx8*)(dst + ((size_t)b * 4096 + y * 64 + wo) * 256 + c0) = pk;
    } else {
        int idx = (blk - 2048) * 256 + t;
        if (idx < CK * COo) {
            // dst (co, k, c) <- reg_w[co*2304 + c*9 + k]
            int co = idx / CK;
            int r  = idx - co * CK;
            int k  = r >> 8;
            int c  = r & 255;
            Wbf[idx] = __float2bfloat16(reg_w[(size_t)co * CK + c * 9 + k]);
        }
        if (idx < 147456) {
            int g    = idx / 73728;
            int rem  = idx % 73728;
            int kc   = rem / 9216;
            int r2   = rem % 9216;
            int tap  = r2 / 1024;
            int r3   = r2 & 1023;
            int nf   = r3 >> 9;
            int r4   = r3 & 511;
            int lane = r4 >> 3;
            int j    = r4 & 7;
            int c    = kc * 32 + (lane >> 4) * 8 + j;
            int n    = nf * 16 + (lane & 15);
            float v = 0.f;
            if (g == 0) { if (n < 18) v = off_w[((size_t)n * CC + c) * 9 + tap]; }
            else        { if (n < 9)  v = mod_w[((size_t)n * CC + c) * 9 + tap]; }
            Wpk[idx] = __float2bfloat16(v);
        }
    }
}

// ---------------------------------------------------------------------------
// K1: DIRECT offset+modulator conv. (R11-validated structure; R15 trim:
// g=1 only produces n<9, so the acc1/b1 path (n>=16) is skipped for g=1 —
// block-uniform branch; acc1 stays zero and the n<9 epilogue mask is
// unchanged.)
// ---------------------------------------------------------------------------
__global__ __launch_bounds__(512) void convA2_kernel(
    const __hip_bfloat16* __restrict__ xT,
    const __hip_bfloat16* __restrict__ resT,
    const __hip_bfloat16* __restrict__ Wpk,
    const float* __restrict__ off_b,
    const float* __restrict__ mod_b,
    float* __restrict__ off_out,
    float* __restrict__ mask_out)
{
    int blk = blockIdx.x;
    int tile = blk & 127;
    int g = (blk >> 7) & 1;
    int b = blk >> 8;
    int t = threadIdx.x;
    int lane = t & 63;
    int w = t >> 6;                  // 0..7
    int ph = w & 1;                  // pixel half (16 pixels)
    int ks = w >> 1;                 // K quarter (kc pair)
    int ln = lane & 15;
    int quad = lane >> 4;

    const __hip_bfloat16* src = (g ? xT : resT) + (size_t)b * 4096 * 256;
    const __hip_bfloat16* wg  = Wpk + (size_t)g * 73728 + (size_t)ks * 2 * 9216;

    int pix = tile * 32 + ph * 16 + ln;   // this lane's A-row (pixel)
    int ho = pix >> 6, wo = pix & 63;

    floatx4 acc0 = (floatx4){0.f, 0.f, 0.f, 0.f};
    floatx4 acc1 = (floatx4){0.f, 0.f, 0.f, 0.f};

#pragma unroll
    for (int tap = 0; tap < 9; ++tap) {
        int ky = tap / 3, kx = tap % 3;
        int r  = ho + ky - 1;
        int cx = wo + kx - 1;
        bool v = (r >= 0) && (r < HH) && (cx >= 0) && (cx < WW);
        int hw = v ? (r * WW + cx) : 0;
        const __hip_bfloat16* abase = src + (size_t)hw * 256 + quad * 8 + ks * 64;
        const __hip_bfloat16* wbase = wg + (size_t)tap * 1024 + lane * 8;
#pragma unroll
        for (int kc = 0; kc < 2; ++kc) {
            shortx8 af = *(const shortx8*)(abase + kc * 32);
            if (!v) {
                shortx8 zf = {0,0,0,0,0,0,0,0};
                af = zf;
            }
            shortx8 b0 = *(const shortx8*)(wbase + (size_t)kc * 9216);
            acc0 = __builtin_amdgcn_mfma_f32_16x16x32_bf16(af, b0, acc0, 0, 0, 0);
            if (g == 0) {
                shortx8 b1 = *(const shortx8*)(wbase + (size_t)kc * 9216 + 512);
                acc1 = __builtin_amdgcn_mfma_f32_16x16x32_bf16(af, b1, acc1, 0, 0, 0);
            }
        }
    }

    __shared__ float s_red[8][64][8];    // 16 KB
    *(floatx4*)&s_red[w][lane][0] = acc0;
    *(floatx4*)&s_red[w][lane][4] = acc1;
    __syncthreads();
    if (w < 2) {                         // w == ph, ks == 0
#pragma unroll
        for (int j = 0; j < 4; ++j) {
            acc0[j] = s_red[w][lane][j]     + s_red[w + 2][lane][j]
                    + s_red[w + 4][lane][j] + s_red[w + 6][lane][j];
            acc1[j] = s_red[w][lane][4 + j]     + s_red[w + 2][lane][4 + j]
                    + s_red[w + 4][lane][4 + j] + s_red[w + 6][lane][4 + j];
        }

#pragma unroll
        for (int nf = 0; nf < 2; ++nf) {
            floatx4 a = nf ? acc1 : acc0;
            int n = nf * 16 + ln;
#pragma unroll
            for (int i2 = 0; i2 < 4; ++i2) {
                int p = tile * 32 + w * 16 + quad * 4 + i2;
                if (g == 0) {
                    if (n < 18)
                        off_out[((size_t)b * 18 + n) * HWs + p] = a[i2] + off_b[n];
                } else {
                    if (n < 9) {
                        float z = a[i2] + mod_b[n];
                        mask_out[((size_t)b * 9 + n) * HWs + p] =
                            2.f / (1.f + __expf(-z));
                    }
                }
            }
        }
    }
}

// ---------------------------------------------------------------------------
// K2 (R15): FUSED gather+GEMM, BN=256 (nt merged). grid 256 (one block per
// 32-pixel tile), block 512 = 8 waves (wm = w&1: 16-pixel half; wn = w>>1:
// 64-co quarter). Each mt's A-gather and B-DMA now happen ONCE (R14 did both
// twice via the nt pair): B traffic 295->147 MB, gather loads halved.
// Same validated sync skeleton: one __syncthreads per K-step, dbuf B-DMA
// with pre-swizzled global src, XOR read swizzle, per-wave LDS epilogue.
// Accumulation order per output is bit-identical to R14.
// XCD swizzle gives each XCD a contiguous 32-mt run -> per-batch xT (4.2 MB)
// ~L2-resident for the gather.
// LDS: As 8K + Bs 64K + meta 9K + s_out 10K = 91 KB -> 1 block/CU (grid=1/CU).
// ---------------------------------------------------------------------------
__global__ __launch_bounds__(512) void gemm_fused_kernel(
    const __hip_bfloat16* __restrict__ xT,
    const float* __restrict__ off,
    const float* __restrict__ mask,
    const __hip_bfloat16* __restrict__ Wbf,
    float* __restrict__ out)
{
    int blk0 = blockIdx.x;
    int mt = ((blk0 & 7) << 5) | (blk0 >> 3);   // XCD chunking, bijective on 256
    int t  = threadIdx.x;
    int lane = t & 63;
    int w    = t >> 6;              // 0..7
    int quad = lane >> 4;
    int ln   = lane & 15;
    int wm = w & 1;                 // M half (16 rows)
    int wn = w >> 1;                // N quarter (64 cols)

    __shared__ __hip_bfloat16 As[2][32 * 64];    // 8 KB
    __shared__ __hip_bfloat16 Bs[2][256 * 64];   // 64 KB
    __shared__ int   s_mi[32][K2][4];            // 4.5 KB corner indices
    __shared__ float s_mw[32][K2][4];            // 4.5 KB corner weights (x mask)
    __shared__ float s_out[8][16 * 20];          // 10 KB epilogue

    int b = mt >> 7;
    const __hip_bfloat16* xb = xT + (size_t)b * 4096 * 256;

    int lr8 = lane >> 3;            // staging row within 8
    int sub = lane & 7;             // 16B slot
    int chk = sub ^ lr8;            // pre-swizzled global k-chunk

    // wave w stages B rows {h*64 + w*8 + lr8 : h=0..3} (4 gll16/step)
    const __hip_bfloat16* gB = Wbf + (size_t)(w * 8 + lr8) * CK + chk * 8;

    floatx4 acc[4];
#pragma unroll
    for (int nf = 0; nf < 4; ++nf) acc[nf] = (floatx4){0.f, 0.f, 0.f, 0.f};

    // issue B buf0 DMA first (latency overlaps meta compute)
#pragma unroll
    for (int h = 0; h < 4; ++h)
        gll16(gB + (size_t)(h * 64) * CK, &Bs[0][h * 4096 + w * 512]);

    // ---- meta prologue: corner idx/weights for 32 pixels x 9 taps ----
    for (int u = t; u < 32 * K2; u += 512) {
        int pl = u / K2;
        int k  = u - pl * K2;
        int pix = mt * 32 + pl;
        int hw = pix & 4095;
        int ho = hw >> 6, wo = hw & 63;
        float dy = off [(((size_t)b * 18 + 2 * k    ) << 12) + hw];
        float dx = off [(((size_t)b * 18 + 2 * k + 1) << 12) + hw];
        float m  = mask[(((size_t)b * 9  + k        ) << 12) + hw];
        float py = (float)(ho - 1 + k / 3) + dy;
        float px = (float)(wo - 1 + k % 3) + dx;
        float y0f = floorf(py), x0f = floorf(px);
        float wy1 = py - y0f, wx1 = px - x0f;
        float wy0 = 1.f - wy1, wx0 = 1.f - wx1;
        int y0 = (int)y0f, x0 = (int)x0f;
#pragma unroll
        for (int j = 0; j < 4; ++j) {
            int yy = y0 + (j >> 1);
            int xx = x0 + (j & 1);
            float wj = ((j == 0) ? wy0 * wx0 :
                        (j == 1) ? wy0 * wx1 :
                        (j == 2) ? wy1 * wx0 : wy1 * wx1) * m;
            bool valid = (yy >= 0) && (yy < HH) && (xx >= 0) && (xx < WW);
            s_mi[pl][k][j] = valid ? (yy * WW + xx) : 0;
            s_mw[pl][k][j] = valid ? wj : 0.f;
        }
    }

    // gather workers: threads 0..255 (waves 0-3); pl = pixel, ch8 = 8-ch group
    int pl  = t >> 3;               // 0..63 (only <32 used; t<256 -> pl<32)
    int ch8 = t & 7;
    int aslot = (pl & 31) * 64 + ((ch8 ^ (pl & 7)) * 8);   // swizzled As column

    auto gather = [&](int buf, int kt1) {
        int k  = kt1 >> 2;
        int cb = kt1 & 3;
        int i0 = s_mi[pl & 31][k][0], i1 = s_mi[pl & 31][k][1];
        int i2 = s_mi[pl & 31][k][2], i3 = s_mi[pl & 31][k][3];
        float w0 = s_mw[pl & 31][k][0], w1 = s_mw[pl & 31][k][1];
        float w2 = s_mw[pl & 31][k][2], w3 = s_mw[pl & 31][k][3];
        const __hip_bfloat16* xr = xb + cb * 64 + ch8 * 8;
        shortx8 c0 = *(const shortx8*)(xr + (size_t)i0 * 256);
        shortx8 c1 = *(const shortx8*)(xr + (size_t)i1 * 256);
        shortx8 c2 = *(const shortx8*)(xr + (size_t)i2 * 256);
        shortx8 c3 = *(const shortx8*)(xr + (size_t)i3 * 256);
        shortx8 o;
#pragma unroll
        for (int j = 0; j < 8; ++j)
            o[j] = f2bf(w0 * bf2f(c0[j]) + w1 * bf2f(c1[j])
                      + w2 * bf2f(c2[j]) + w3 * bf2f(c3[j]));
        *(shortx8*)&As[buf][aslot] = o;
    };

    __syncthreads();                // meta visible (also drains B0 DMA)
    if (t < 256) gather(0, 0);

    int swz = ln & 7;               // read-slot XOR key

    for (int kt = 0; kt < 36; ++kt) {
        int cur = kt & 1;
        int nxt = cur ^ 1;
        __syncthreads();            // buf[cur] staged; buf[nxt] reads done
        if (kt + 1 < 36) {
            int ko = (kt + 1) * 64;
#pragma unroll
            for (int h = 0; h < 4; ++h)
                gll16(gB + (size_t)(h * 64) * CK + ko, &Bs[nxt][h * 4096 + w * 512]);
        }
#pragma unroll
        for (int kh = 0; kh < 2; ++kh) {
            int slot = ((kh * 4 + quad) ^ swz) * 8;
            shortx8 af = *(const shortx8*)
                &As[cur][(wm * 16 + ln) * 64 + slot];
            shortx8 bf[4];
#pragma unroll
            for (int nf = 0; nf < 4; ++nf)
                bf[nf] = *(const shortx8*)
                    &Bs[cur][(wn * 64 + nf * 16 + ln) * 64 + slot];
#pragma unroll
            for (int nf = 0; nf < 4; ++nf)
                acc[nf] = __builtin_amdgcn_mfma_f32_16x16x32_bf16(
                    af, bf[nf], acc[nf], 0, 0, 0);
        }
        if (kt + 1 < 36 && t < 256) gather(nxt, kt + 1);
    }

    // epilogue: per-wave LDS transpose (s_out region disjoint; no barrier)
    int bb = mt >> 7;
    int hw0 = (mt & 127) * 32 + wm * 16;
    float* sw = &s_out[w][0];
    int co_l = lane >> 2;
    int seg  = lane & 3;
#pragma unroll
    for (int nf = 0; nf < 4; ++nf) {
        *(floatx4*)&sw[ln * 20 + quad * 4] = acc[nf];
        floatx4 v0 = *(const floatx4*)&sw[co_l * 20 + seg * 4];
        int co = wn * 64 + nf * 16 + co_l;
        float* orow = out + ((size_t)(bb * COo + co) << 12) + hw0;
        *(floatx4*)&orow[seg * 4] = v0;
    }
}

// ---------------------------------------------------------------------------
extern "C" void kernel_launch(void* const* d_in, const int* in_sizes, int n_in,
                              void* d_out, int out_size, void* d_ws, size_t ws_size,
                              hipStream_t stream)
{
    const float* x     = (const float*)d_in[0];
    const float* resid = (const float*)d_in[1];
    const float* off_w = (const float*)d_in[2];
    const float* off_b = (const float*)d_in[3];
    const float* mod_w = (const float*)d_in[4];
    const float* mod_b = (const float*)d_in[5];
    const float* reg_w = (const float*)d_in[6];
    float* out = (float*)d_out;

    float* ws = (float*)d_ws;
    float* off_buf   = ws + O_OFF;
    float* mask_buf  = ws + O_MASK;
    __hip_bfloat16* Wbf  = (__hip_bfloat16*)(ws + O_WBF);
    __hip_bfloat16* Wpk  = (__hip_bfloat16*)(ws + O_WPK);
    __hip_bfloat16* xT   = (__hip_bfloat16*)(ws + O_XT);
    __hip_bfloat16* resT = (__hip_bfloat16*)(ws + O_RT);

    // fused transpose (2048 blocks) + weight pack (2304 blocks)
    prep_kernel<<<2048 + (CK * COo + 255) / 256, 256, 0, stream>>>(
        x, resid, reg_w, off_w, mod_w, xT, resT, Wbf, Wpk);

    convA2_kernel<<<512, 512, 0, stream>>>(xT, resT, Wpk, off_b, mod_b,
                                           off_buf, mask_buf);

    gemm_fused_kernel<<<256, 512, 0, stream>>>(xT, off_buf, mask_buf, Wbf, out);
}

// Round 6
// 136.722 us; speedup vs baseline: 1.0342x; 1.0342x over previous
//
#include <hip/hip_runtime.h>
#include <hip/hip_bf16.h>
#include <math.h>

// Problem constants (B=2, C=256, H=W=64, Co=256, 3x3, stride1, pad1)
#define BB 2
#define CC 256
#define HH 64
#define WW 64
#define COo 256
#define HWs 4096
#define K2 9
#define CK 2304   // C*9

typedef __attribute__((ext_vector_type(4))) float floatx4;
typedef __attribute__((ext_vector_type(8))) short shortx8;   // 8 bf16

// ---- workspace layout (float units) ----
#define O_OFF   0          // final offset  B*18*4096 = 147456 f
#define O_MASK  147456     // final modulator B*9*4096 = 73728 f
#define O_WBF   221184     // reg_w bf16 [co][k*256+c] = 294912 f  (tap-major)
#define O_WPK   516096     // convA weights [g2][kc8][tap9][nf2][lane][8] = 73728 f
#define O_XT    10027008   // x NHWC bf16 [b][y][x][c] = 1048576 f
#define O_RT    11075584   // residual NHWC bf16 = 1048576 f

__device__ __forceinline__ void gll16(const __hip_bfloat16* g, __hip_bfloat16* l) {
    __builtin_amdgcn_global_load_lds(
        (const __attribute__((address_space(1))) unsigned int*)g,
        (__attribute__((address_space(3))) unsigned int*)l, 16, 0, 0);
}

__device__ __forceinline__ short f2bf(float v) {
    __hip_bfloat16 h = __float2bfloat16(v);
    return *reinterpret_cast<short*>(&h);
}

__device__ __forceinline__ float bf2f(short s) {
    unsigned u = ((unsigned)(unsigned short)s) << 16;
    return __builtin_bit_cast(float, u);
}

// ---------------------------------------------------------------------------
// K0: FUSED prep = transpose (blocks 0..2047) + weight pack (blocks 2048+).
// Wbf tap-major: Wbf[co*2304 + k*256 + c] = reg_w[co][c][k]. (verbatim R14)
// ---------------------------------------------------------------------------
__global__ __launch_bounds__(256) void prep_kernel(
    const float* __restrict__ x,
    const float* __restrict__ residual,
    const float* __restrict__ reg_w,
    const float* __restrict__ off_w,
    const float* __restrict__ mod_w,
    __hip_bfloat16* __restrict__ xT,
    __hip_bfloat16* __restrict__ resT,
    __hip_bfloat16* __restrict__ Wbf,
    __hip_bfloat16* __restrict__ Wpk)
{
    int blk = blockIdx.x;
    int t = threadIdx.x;
    if (blk < 2048) {
        int sel = blk >> 10;             // 0 = x, 1 = residual
        int bk  = blk & 1023;            // ((b*64 + y)*8 + oc)
        int oc = bk & 7;
        int y  = (bk >> 3) & 63;
        int b  = bk >> 9;
        int wo = t & 63;
        int cg = t >> 6;
        int c0 = oc * 32 + cg * 8;
        const float* src = (sel ? residual : x)
                           + ((size_t)(b * CC + c0) * HH + y) * WW + wo;
        shortx8 pk;
#pragma unroll
        for (int j = 0; j < 8; ++j) pk[j] = f2bf(src[(size_t)j * HWs]);
        __hip_bfloat16* dst = sel ? resT : xT;
        *(shortx8*)(dst + ((size_t)b * 4096 + y * 64 + wo) * 256 + c0) = pk;
    } else {
        int idx = (blk - 2048) * 256 + t;
        if (idx < CK * COo) {
            // dst (co, k, c) <- reg_w[co*2304 + c*9 + k]
            int co = idx / CK;
            int r  = idx - co * CK;
            int k  = r >> 8;
            int c  = r & 255;
            Wbf[idx] = __float2bfloat16(reg_w[(size_t)co * CK + c * 9 + k]);
        }
        if (idx < 147456) {
            int g    = idx / 73728;
            int rem  = idx % 73728;
            int kc   = rem / 9216;
            int r2   = rem % 9216;
            int tap  = r2 / 1024;
            int r3   = r2 & 1023;
            int nf   = r3 >> 9;
            int r4   = r3 & 511;
            int lane = r4 >> 3;
            int j    = r4 & 7;
            int c    = kc * 32 + (lane >> 4) * 8 + j;
            int n    = nf * 16 + (lane & 15);
            float v = 0.f;
            if (g == 0) { if (n < 18) v = off_w[((size_t)n * CC + c) * 9 + tap]; }
            else        { if (n < 9)  v = mod_w[((size_t)n * CC + c) * 9 + tap]; }
            Wpk[idx] = __float2bfloat16(v);
        }
    }
}

// ---------------------------------------------------------------------------
// K1: DIRECT offset+modulator conv. (R11-validated structure; R15 trim:
// g=1 only produces n<9 -> acc1/b1 path skipped for g=1, block-uniform.)
// ---------------------------------------------------------------------------
__global__ __launch_bounds__(512) void convA2_kernel(
    const __hip_bfloat16* __restrict__ xT,
    const __hip_bfloat16* __restrict__ resT,
    const __hip_bfloat16* __restrict__ Wpk,
    const float* __restrict__ off_b,
    const float* __restrict__ mod_b,
    float* __restrict__ off_out,
    float* __restrict__ mask_out)
{
    int blk = blockIdx.x;
    int tile = blk & 127;
    int g = (blk >> 7) & 1;
    int b = blk >> 8;
    int t = threadIdx.x;
    int lane = t & 63;
    int w = t >> 6;                  // 0..7
    int ph = w & 1;                  // pixel half (16 pixels)
    int ks = w >> 1;                 // K quarter (kc pair)
    int ln = lane & 15;
    int quad = lane >> 4;

    const __hip_bfloat16* src = (g ? xT : resT) + (size_t)b * 4096 * 256;
    const __hip_bfloat16* wg  = Wpk + (size_t)g * 73728 + (size_t)ks * 2 * 9216;

    int pix = tile * 32 + ph * 16 + ln;   // this lane's A-row (pixel)
    int ho = pix >> 6, wo = pix & 63;

    floatx4 acc0 = (floatx4){0.f, 0.f, 0.f, 0.f};
    floatx4 acc1 = (floatx4){0.f, 0.f, 0.f, 0.f};

#pragma unroll
    for (int tap = 0; tap < 9; ++tap) {
        int ky = tap / 3, kx = tap % 3;
        int r  = ho + ky - 1;
        int cx = wo + kx - 1;
        bool v = (r >= 0) && (r < HH) && (cx >= 0) && (cx < WW);
        int hw = v ? (r * WW + cx) : 0;
        const __hip_bfloat16* abase = src + (size_t)hw * 256 + quad * 8 + ks * 64;
        const __hip_bfloat16* wbase = wg + (size_t)tap * 1024 + lane * 8;
#pragma unroll
        for (int kc = 0; kc < 2; ++kc) {
            shortx8 af = *(const shortx8*)(abase + kc * 32);
            if (!v) {
                shortx8 zf = {0,0,0,0,0,0,0,0};
                af = zf;
            }
            shortx8 b0 = *(const shortx8*)(wbase + (size_t)kc * 9216);
            acc0 = __builtin_amdgcn_mfma_f32_16x16x32_bf16(af, b0, acc0, 0, 0, 0);
            if (g == 0) {
                shortx8 b1 = *(const shortx8*)(wbase + (size_t)kc * 9216 + 512);
                acc1 = __builtin_amdgcn_mfma_f32_16x16x32_bf16(af, b1, acc1, 0, 0, 0);
            }
        }
    }

    __shared__ float s_red[8][64][8];    // 16 KB
    *(floatx4*)&s_red[w][lane][0] = acc0;
    *(floatx4*)&s_red[w][lane][4] = acc1;
    __syncthreads();
    if (w < 2) {                         // w == ph, ks == 0
#pragma unroll
        for (int j = 0; j < 4; ++j) {
            acc0[j] = s_red[w][lane][j]     + s_red[w + 2][lane][j]
                    + s_red[w + 4][lane][j] + s_red[w + 6][lane][j];
            acc1[j] = s_red[w][lane][4 + j]     + s_red[w + 2][lane][4 + j]
                    + s_red[w + 4][lane][4 + j] + s_red[w + 6][lane][4 + j];
        }

#pragma unroll
        for (int nf = 0; nf < 2; ++nf) {
            floatx4 a = nf ? acc1 : acc0;
            int n = nf * 16 + ln;
#pragma unroll
            for (int i2 = 0; i2 < 4; ++i2) {
                int p = tile * 32 + w * 16 + quad * 4 + i2;
                if (g == 0) {
                    if (n < 18)
                        off_out[((size_t)b * 18 + n) * HWs + p] = a[i2] + off_b[n];
                } else {
                    if (n < 9) {
                        float z = a[i2] + mod_b[n];
                        mask_out[((size_t)b * 9 + n) * HWs + p] =
                            2.f / (1.f + __expf(-z));
                    }
                }
            }
        }
    }
}

// ---------------------------------------------------------------------------
// K2 (R16): FUSED gather+GEMM = R14 geometry (grid 512 = mt256 x nt2, block
// 256 = 4 waves, 54 KB LDS -> 2 blocks/CU) + T14 async-gather split.
// R15's BN=256 merge REGRESSED (+9 us; counters: MfmaUtil 7.5%, occ 19%,
// FETCH 7.8 MB -> latency-bound at 1 block/CU, gather chain exposed at step
// tail). R16 keeps the validated R14 barrier skeleton byte-for-byte and only
// reschedules within the step: corner loads for kt+1 are ISSUED into
// registers right after the barrier (before B-DMA + MFMA); the FMA+pack+
// ds_write lands after the MFMA phase. Per-tap meta (s_mi/s_mw) is cached
// in registers across the 4 channel-block steps sharing a tap, removing the
// LDS-read head from the load chain. Hazards unchanged from R14 proof.
// ---------------------------------------------------------------------------
__global__ __launch_bounds__(256) void gemm_fused_kernel(
    const __hip_bfloat16* __restrict__ xT,
    const float* __restrict__ off,
    const float* __restrict__ mask,
    const __hip_bfloat16* __restrict__ Wbf,
    float* __restrict__ out)
{
    int blk0 = blockIdx.x;
    int blk = ((blk0 & 7) << 6) | (blk0 >> 3);   // XCD chunking, bijective on 512
    int nt = blk & 1;
    int mt = blk >> 1;              // 0..255 (32-pixel tiles)
    int t  = threadIdx.x;
    int lane = t & 63;
    int w    = t >> 6;              // 0..3
    int quad = lane >> 4;
    int ln   = lane & 15;
    int wm = w & 1;                 // M half (16 rows)
    int wn = w >> 1;                // N half (64 cols)

    __shared__ __hip_bfloat16 As[2][32 * 64];    // 8 KB
    __shared__ __hip_bfloat16 Bs[2][128 * 64];   // 32 KB
    __shared__ int   s_mi[32][K2][4];            // 4.5 KB corner indices
    __shared__ float s_mw[32][K2][4];            // 4.5 KB corner weights (x mask)
    __shared__ float s_out[4][16 * 20];          // 5 KB epilogue
    // total 54 KB -> 2 blocks/CU

    int b = mt >> 7;
    const __hip_bfloat16* xb = xT + (size_t)b * 4096 * 256;

    int lr8 = lane >> 3;            // staging row within 8
    int sub = lane & 7;             // 16B slot
    int chk = sub ^ lr8;            // pre-swizzled global k-chunk

    const __hip_bfloat16* gB = Wbf + (size_t)(nt * 128 + w * 8 + lr8) * CK + chk * 8;
    int lof = w * 512;

    floatx4 acc[4];
#pragma unroll
    for (int nf = 0; nf < 4; ++nf) acc[nf] = (floatx4){0.f, 0.f, 0.f, 0.f};

    // issue B buf0 DMA first (latency overlaps meta compute)
#pragma unroll
    for (int h = 0; h < 4; ++h)
        gll16(gB + (size_t)(h * 32) * CK, &Bs[0][lof + h * 2048]);

    // ---- meta prologue: corner idx/weights for 32 pixels x 9 taps ----
    for (int u = t; u < 32 * K2; u += 256) {
        int pl_ = u / K2;
        int k  = u - pl_ * K2;
        int pix = mt * 32 + pl_;
        int hw = pix & 4095;
        int ho = hw >> 6, wo = hw & 63;
        float dy = off [(((size_t)b * 18 + 2 * k    ) << 12) + hw];
        float dx = off [(((size_t)b * 18 + 2 * k + 1) << 12) + hw];
        float m  = mask[(((size_t)b * 9  + k        ) << 12) + hw];
        float py = (float)(ho - 1 + k / 3) + dy;
        float px = (float)(wo - 1 + k % 3) + dx;
        float y0f = floorf(py), x0f = floorf(px);
        float wy1 = py - y0f, wx1 = px - x0f;
        float wy0 = 1.f - wy1, wx0 = 1.f - wx1;
        int y0 = (int)y0f, x0 = (int)x0f;
#pragma unroll
        for (int j = 0; j < 4; ++j) {
            int yy = y0 + (j >> 1);
            int xx = x0 + (j & 1);
            float wj = ((j == 0) ? wy0 * wx0 :
                        (j == 1) ? wy0 * wx1 :
                        (j == 2) ? wy1 * wx0 : wy1 * wx1) * m;
            bool valid = (yy >= 0) && (yy < HH) && (xx >= 0) && (xx < WW);
            s_mi[pl_][k][j] = valid ? (yy * WW + xx) : 0;
            s_mw[pl_][k][j] = valid ? wj : 0.f;
        }
    }

    int pl  = t >> 3;               // gather: this thread's pixel (0..31)
    int ch8 = t & 7;                // gather: 8-channel group within 64
    int aslot = pl * 64 + ((ch8 ^ (pl & 7)) * 8);   // swizzled As column

    // per-tap meta cached in registers (reloaded every 4 K-steps)
    int   mi0, mi1, mi2, mi3;
    float mw0, mw1, mw2, mw3;
    auto meta_load = [&](int k) {
        mi0 = s_mi[pl][k][0]; mi1 = s_mi[pl][k][1];
        mi2 = s_mi[pl][k][2]; mi3 = s_mi[pl][k][3];
        mw0 = s_mw[pl][k][0]; mw1 = s_mw[pl][k][1];
        mw2 = s_mw[pl][k][2]; mw3 = s_mw[pl][k][3];
    };

    // in-flight gather state (T14 split: issue-early / finish-late)
    shortx8 gc0, gc1, gc2, gc3;
    auto gather_load = [&](int cb) {
        const __hip_bfloat16* xr = xb + cb * 64 + ch8 * 8;
        gc0 = *(const shortx8*)(xr + (size_t)mi0 * 256);
        gc1 = *(const shortx8*)(xr + (size_t)mi1 * 256);
        gc2 = *(const shortx8*)(xr + (size_t)mi2 * 256);
        gc3 = *(const shortx8*)(xr + (size_t)mi3 * 256);
    };
    auto gather_store = [&](int buf) {
        shortx8 o;
#pragma unroll
        for (int j = 0; j < 8; ++j)
            o[j] = f2bf(mw0 * bf2f(gc0[j]) + mw1 * bf2f(gc1[j])
                      + mw2 * bf2f(gc2[j]) + mw3 * bf2f(gc3[j]));
        *(shortx8*)&As[buf][aslot] = o;
    };

    __syncthreads();                // meta visible (also drains B0 DMA)
    meta_load(0);
    gather_load(0);
    gather_store(0);

    int swz = ln & 7;               // read-slot XOR key

    for (int kt = 0; kt < 36; ++kt) {
        int cur = kt & 1;
        int nxt = cur ^ 1;
        __syncthreads();            // buf[cur] staged; buf[nxt] reads done
        if (kt + 1 < 36) {
            int kt1 = kt + 1;
            if ((kt1 & 3) == 0) meta_load(kt1 >> 2);
            gather_load(kt1 & 3);   // issue corner loads early (finish below)
            int ko = kt1 * 64;
#pragma unroll
            for (int h = 0; h < 4; ++h)
                gll16(gB + (size_t)(h * 32) * CK + ko, &Bs[nxt][lof + h * 2048]);
        }
#pragma unroll
        for (int kh = 0; kh < 2; ++kh) {
            int slot = ((kh * 4 + quad) ^ swz) * 8;
            shortx8 af = *(const shortx8*)
                &As[cur][(wm * 16 + ln) * 64 + slot];
            shortx8 bf[4];
#pragma unroll
            for (int nf = 0; nf < 4; ++nf)
                bf[nf] = *(const shortx8*)
                    &Bs[cur][(wn * 64 + nf * 16 + ln) * 64 + slot];
#pragma unroll
            for (int nf = 0; nf < 4; ++nf)
                acc[nf] = __builtin_amdgcn_mfma_f32_16x16x32_bf16(
                    af, bf[nf], acc[nf], 0, 0, 0);
        }
        if (kt + 1 < 36) gather_store(nxt);   // finish: FMA + pack + ds_write
    }

    // epilogue (verbatim R13/R14): per-wave LDS transpose
    int bb = mt >> 7;
    int hw0 = (mt & 127) * 32 + wm * 16;
    float* sw = &s_out[w][0];
    int co_l = lane >> 2;
    int seg  = lane & 3;
#pragma unroll
    for (int nf = 0; nf < 4; ++nf) {
        *(floatx4*)&sw[ln * 20 + quad * 4] = acc[nf];
        floatx4 v0 = *(const floatx4*)&sw[co_l * 20 + seg * 4];
        int co = nt * 128 + wn * 64 + nf * 16 + co_l;
        float* orow = out + ((size_t)(bb * COo + co) << 12) + hw0;
        *(floatx4*)&orow[seg * 4] = v0;
    }
}

// ---------------------------------------------------------------------------
extern "C" void kernel_launch(void* const* d_in, const int* in_sizes, int n_in,
                              void* d_out, int out_size, void* d_ws, size_t ws_size,
                              hipStream_t stream)
{
    const float* x     = (const float*)d_in[0];
    const float* resid = (const float*)d_in[1];
    const float* off_w = (const float*)d_in[2];
    const float* off_b = (const float*)d_in[3];
    const float* mod_w = (const float*)d_in[4];
    const float* mod_b = (const float*)d_in[5];
    const float* reg_w = (const float*)d_in[6];
    float* out = (float*)d_out;

    float* ws = (float*)d_ws;
    float* off_buf   = ws + O_OFF;
    float* mask_buf  = ws + O_MASK;
    __hip_bfloat16* Wbf  = (__hip_bfloat16*)(ws + O_WBF);
    __hip_bfloat16* Wpk  = (__hip_bfloat16*)(ws + O_WPK);
    __hip_bfloat16* xT   = (__hip_bfloat16*)(ws + O_XT);
    __hip_bfloat16* resT = (__hip_bfloat16*)(ws + O_RT);

    // fused transpose (2048 blocks) + weight pack (2304 blocks)
    prep_kernel<<<2048 + (CK * COo + 255) / 256, 256, 0, stream>>>(
        x, resid, reg_w, off_w, mod_w, xT, resT, Wbf, Wpk);

    convA2_kernel<<<512, 512, 0, stream>>>(xT, resT, Wpk, off_b, mod_b,
                                           off_buf, mask_buf);

    gemm_fused_kernel<<<512, 256, 0, stream>>>(xT, off_buf, mask_buf, Wbf, out);
}

// Round 7
// 130.565 us; speedup vs baseline: 1.0830x; 1.0472x over previous
//
#include <hip/hip_runtime.h>
#include <hip/hip_bf16.h>
#include <math.h>

// Problem constants (B=2, C=256, H=W=64, Co=256, 3x3, stride1, pad1)
#define BB 2
#define CC 256
#define HH 64
#define WW 64
#define COo 256
#define HWs 4096
#define K2 9
#define CK 2304   // C*9

typedef __attribute__((ext_vector_type(4))) float floatx4;
typedef __attribute__((ext_vector_type(8))) short shortx8;   // 8 bf16

// ---- workspace layout (float units) ----
#define O_OFF   0          // final offset  B*18*4096 = 147456 f
#define O_MASK  147456     // final modulator B*9*4096 = 73728 f
#define O_WBF   221184     // reg_w bf16 [co][k*256+c] = 294912 f  (tap-major)
#define O_WPK   516096     // convA weights [g2][kc8][tap9][nf2][lane][8] = 73728 f
#define O_XT    10027008   // x NHWC bf16 [b][y][x][c] = 1048576 f
#define O_RT    11075584   // residual NHWC bf16 = 1048576 f

__device__ __forceinline__ void gll16(const __hip_bfloat16* g, __hip_bfloat16* l) {
    __builtin_amdgcn_global_load_lds(
        (const __attribute__((address_space(1))) unsigned int*)g,
        (__attribute__((address_space(3))) unsigned int*)l, 16, 0, 0);
}

__device__ __forceinline__ short f2bf(float v) {
    __hip_bfloat16 h = __float2bfloat16(v);
    return *reinterpret_cast<short*>(&h);
}

__device__ __forceinline__ float bf2f(short s) {
    unsigned u = ((unsigned)(unsigned short)s) << 16;
    return __builtin_bit_cast(float, u);
}

// ---------------------------------------------------------------------------
// K0: FUSED prep = transpose (blocks 0..2047) + weight pack (blocks 2048+).
// Wbf tap-major: Wbf[co*2304 + k*256 + c] = reg_w[co][c][k]. (verbatim R14)
// ---------------------------------------------------------------------------
__global__ __launch_bounds__(256) void prep_kernel(
    const float* __restrict__ x,
    const float* __restrict__ residual,
    const float* __restrict__ reg_w,
    const float* __restrict__ off_w,
    const float* __restrict__ mod_w,
    __hip_bfloat16* __restrict__ xT,
    __hip_bfloat16* __restrict__ resT,
    __hip_bfloat16* __restrict__ Wbf,
    __hip_bfloat16* __restrict__ Wpk)
{
    int blk = blockIdx.x;
    int t = threadIdx.x;
    if (blk < 2048) {
        int sel = blk >> 10;             // 0 = x, 1 = residual
        int bk  = blk & 1023;            // ((b*64 + y)*8 + oc)
        int oc = bk & 7;
        int y  = (bk >> 3) & 63;
        int b  = bk >> 9;
        int wo = t & 63;
        int cg = t >> 6;
        int c0 = oc * 32 + cg * 8;
        const float* src = (sel ? residual : x)
                           + ((size_t)(b * CC + c0) * HH + y) * WW + wo;
        shortx8 pk;
#pragma unroll
        for (int j = 0; j < 8; ++j) pk[j] = f2bf(src[(size_t)j * HWs]);
        __hip_bfloat16* dst = sel ? resT : xT;
        *(shortx8*)(dst + ((size_t)b * 4096 + y * 64 + wo) * 256 + c0) = pk;
    } else {
        int idx = (blk - 2048) * 256 + t;
        if (idx < CK * COo) {
            // dst (co, k, c) <- reg_w[co*2304 + c*9 + k]
            int co = idx / CK;
            int r  = idx - co * CK;
            int k  = r >> 8;
            int c  = r & 255;
            Wbf[idx] = __float2bfloat16(reg_w[(size_t)co * CK + c * 9 + k]);
        }
        if (idx < 147456) {
            int g    = idx / 73728;
            int rem  = idx % 73728;
            int kc   = rem / 9216;
            int r2   = rem % 9216;
            int tap  = r2 / 1024;
            int r3   = r2 & 1023;
            int nf   = r3 >> 9;
            int r4   = r3 & 511;
            int lane = r4 >> 3;
            int j    = r4 & 7;
            int c    = kc * 32 + (lane >> 4) * 8 + j;
            int n    = nf * 16 + (lane & 15);
            float v = 0.f;
            if (g == 0) { if (n < 18) v = off_w[((size_t)n * CC + c) * 9 + tap]; }
            else        { if (n < 9)  v = mod_w[((size_t)n * CC + c) * 9 + tap]; }
            Wpk[idx] = __float2bfloat16(v);
        }
    }
}

// ---------------------------------------------------------------------------
// K1: DIRECT offset+modulator conv. (verbatim R11/R14 — g-trim of R15/R16
// REVERTED to de-confound: it is a bisection suspect for R16's regression.)
// ---------------------------------------------------------------------------
__global__ __launch_bounds__(512) void convA2_kernel(
    const __hip_bfloat16* __restrict__ xT,
    const __hip_bfloat16* __restrict__ resT,
    const __hip_bfloat16* __restrict__ Wpk,
    const float* __restrict__ off_b,
    const float* __restrict__ mod_b,
    float* __restrict__ off_out,
    float* __restrict__ mask_out)
{
    int blk = blockIdx.x;
    int tile = blk & 127;
    int g = (blk >> 7) & 1;
    int b = blk >> 8;
    int t = threadIdx.x;
    int lane = t & 63;
    int w = t >> 6;                  // 0..7
    int ph = w & 1;                  // pixel half (16 pixels)
    int ks = w >> 1;                 // K quarter (kc pair)
    int ln = lane & 15;
    int quad = lane >> 4;

    const __hip_bfloat16* src = (g ? xT : resT) + (size_t)b * 4096 * 256;
    const __hip_bfloat16* wg  = Wpk + (size_t)g * 73728 + (size_t)ks * 2 * 9216;

    int pix = tile * 32 + ph * 16 + ln;   // this lane's A-row (pixel)
    int ho = pix >> 6, wo = pix & 63;

    floatx4 acc0 = (floatx4){0.f, 0.f, 0.f, 0.f};
    floatx4 acc1 = (floatx4){0.f, 0.f, 0.f, 0.f};

#pragma unroll
    for (int tap = 0; tap < 9; ++tap) {
        int ky = tap / 3, kx = tap % 3;
        int r  = ho + ky - 1;
        int cx = wo + kx - 1;
        bool v = (r >= 0) && (r < HH) && (cx >= 0) && (cx < WW);
        int hw = v ? (r * WW + cx) : 0;
        const __hip_bfloat16* abase = src + (size_t)hw * 256 + quad * 8 + ks * 64;
        const __hip_bfloat16* wbase = wg + (size_t)tap * 1024 + lane * 8;
#pragma unroll
        for (int kc = 0; kc < 2; ++kc) {
            shortx8 af = *(const shortx8*)(abase + kc * 32);
            if (!v) {
                shortx8 zf = {0,0,0,0,0,0,0,0};
                af = zf;
            }
            shortx8 b0 = *(const shortx8*)(wbase + (size_t)kc * 9216);
            shortx8 b1 = *(const shortx8*)(wbase + (size_t)kc * 9216 + 512);
            acc0 = __builtin_amdgcn_mfma_f32_16x16x32_bf16(af, b0, acc0, 0, 0, 0);
            acc1 = __builtin_amdgcn_mfma_f32_16x16x32_bf16(af, b1, acc1, 0, 0, 0);
        }
    }

    __shared__ float s_red[8][64][8];    // 16 KB
    *(floatx4*)&s_red[w][lane][0] = acc0;
    *(floatx4*)&s_red[w][lane][4] = acc1;
    __syncthreads();
    if (w < 2) {                         // w == ph, ks == 0
#pragma unroll
        for (int j = 0; j < 4; ++j) {
            acc0[j] = s_red[w][lane][j]     + s_red[w + 2][lane][j]
                    + s_red[w + 4][lane][j] + s_red[w + 6][lane][j];
            acc1[j] = s_red[w][lane][4 + j]     + s_red[w + 2][lane][4 + j]
                    + s_red[w + 4][lane][4 + j] + s_red[w + 6][lane][4 + j];
        }

#pragma unroll
        for (int nf = 0; nf < 2; ++nf) {
            floatx4 a = nf ? acc1 : acc0;
            int n = nf * 16 + ln;
#pragma unroll
            for (int i2 = 0; i2 < 4; ++i2) {
                int p = tile * 32 + w * 16 + quad * 4 + i2;
                if (g == 0) {
                    if (n < 18)
                        off_out[((size_t)b * 18 + n) * HWs + p] = a[i2] + off_b[n];
                } else {
                    if (n < 9) {
                        float z = a[i2] + mod_b[n];
                        mask_out[((size_t)b * 9 + n) * HWs + p] =
                            2.f / (1.f + __expf(-z));
                    }
                }
            }
        }
    }
}

// ---------------------------------------------------------------------------
// K2 (R17): FUSED gather+GEMM = R14 base (grid 512 = mt256 x nt2, block 256
// = 4 waves, 54 KB LDS -> 2 blocks/CU, validated 132.4) + CROSS-STEP gather
// pipeline. Single change vs R14: corner loads for step kt+2 are issued at
// the TOP of step kt (right after the barrier); the FMA+pack+ds_write for
// step kt+1 runs at the tail of step kt using loads issued one full step
// earlier — which __syncthreads' vmcnt(0) drain at THIS step's barrier has
// already completed -> the consume has ZERO exposed vmem wait (R14 exposed
// ~700cy of L3 tail-latency per step at the tail). Bilinear weights travel
// with the loads in a register snapshot (gw), so meta regs can advance to
// kt+2's tap while the kt+1 store uses its own tap's weights.
// Barrier structure, buffer count, MFMA order: bit-identical to R14.
// ---------------------------------------------------------------------------
__global__ __launch_bounds__(256) void gemm_fused_kernel(
    const __hip_bfloat16* __restrict__ xT,
    const float* __restrict__ off,
    const float* __restrict__ mask,
    const __hip_bfloat16* __restrict__ Wbf,
    float* __restrict__ out)
{
    int blk0 = blockIdx.x;
    int blk = ((blk0 & 7) << 6) | (blk0 >> 3);   // XCD chunking, bijective on 512
    int nt = blk & 1;
    int mt = blk >> 1;              // 0..255 (32-pixel tiles)
    int t  = threadIdx.x;
    int lane = t & 63;
    int w    = t >> 6;              // 0..3
    int quad = lane >> 4;
    int ln   = lane & 15;
    int wm = w & 1;                 // M half (16 rows)
    int wn = w >> 1;                // N half (64 cols)

    __shared__ __hip_bfloat16 As[2][32 * 64];    // 8 KB
    __shared__ __hip_bfloat16 Bs[2][128 * 64];   // 32 KB
    __shared__ int   s_mi[32][K2][4];            // 4.5 KB corner indices
    __shared__ float s_mw[32][K2][4];            // 4.5 KB corner weights (x mask)
    __shared__ float s_out[4][16 * 20];          // 5 KB epilogue
    // total 54 KB -> 2 blocks/CU

    int b = mt >> 7;
    const __hip_bfloat16* xb = xT + (size_t)b * 4096 * 256;

    int lr8 = lane >> 3;            // staging row within 8
    int sub = lane & 7;             // 16B slot
    int chk = sub ^ lr8;            // pre-swizzled global k-chunk

    const __hip_bfloat16* gB = Wbf + (size_t)(nt * 128 + w * 8 + lr8) * CK + chk * 8;
    int lof = w * 512;

    floatx4 acc[4];
#pragma unroll
    for (int nf = 0; nf < 4; ++nf) acc[nf] = (floatx4){0.f, 0.f, 0.f, 0.f};

    // issue B buf0 DMA first (latency overlaps meta compute)
#pragma unroll
    for (int h = 0; h < 4; ++h)
        gll16(gB + (size_t)(h * 32) * CK, &Bs[0][lof + h * 2048]);

    // ---- meta prologue: corner idx/weights for 32 pixels x 9 taps ----
    for (int u = t; u < 32 * K2; u += 256) {
        int pl_ = u / K2;
        int k  = u - pl_ * K2;
        int pix = mt * 32 + pl_;
        int hw = pix & 4095;
        int ho = hw >> 6, wo = hw & 63;
        float dy = off [(((size_t)b * 18 + 2 * k    ) << 12) + hw];
        float dx = off [(((size_t)b * 18 + 2 * k + 1) << 12) + hw];
        float m  = mask[(((size_t)b * 9  + k        ) << 12) + hw];
        float py = (float)(ho - 1 + k / 3) + dy;
        float px = (float)(wo - 1 + k % 3) + dx;
        float y0f = floorf(py), x0f = floorf(px);
        float wy1 = py - y0f, wx1 = px - x0f;
        float wy0 = 1.f - wy1, wx0 = 1.f - wx1;
        int y0 = (int)y0f, x0 = (int)x0f;
#pragma unroll
        for (int j = 0; j < 4; ++j) {
            int yy = y0 + (j >> 1);
            int xx = x0 + (j & 1);
            float wj = ((j == 0) ? wy0 * wx0 :
                        (j == 1) ? wy0 * wx1 :
                        (j == 2) ? wy1 * wx0 : wy1 * wx1) * m;
            bool valid = (yy >= 0) && (yy < HH) && (xx >= 0) && (xx < WW);
            s_mi[pl_][k][j] = valid ? (yy * WW + xx) : 0;
            s_mw[pl_][k][j] = valid ? wj : 0.f;
        }
    }

    int pl  = t >> 3;               // gather: this thread's pixel (0..31)
    int ch8 = t & 7;                // gather: 8-channel group within 64
    int aslot = pl * 64 + ((ch8 ^ (pl & 7)) * 8);   // swizzled As column

    // per-tap meta (for the step currently being LOADED)
    int   mi0, mi1, mi2, mi3;
    float mw0, mw1, mw2, mw3;
    auto meta_load = [&](int k) {
        mi0 = s_mi[pl][k][0]; mi1 = s_mi[pl][k][1];
        mi2 = s_mi[pl][k][2]; mi3 = s_mi[pl][k][3];
        mw0 = s_mw[pl][k][0]; mw1 = s_mw[pl][k][1];
        mw2 = s_mw[pl][k][2]; mw3 = s_mw[pl][k][3];
    };

    // in-flight gather state: loaded corners + their weights (snapshot)
    shortx8 gc0, gc1, gc2, gc3;
    float   gw0, gw1, gw2, gw3;
    auto gather_load = [&](int cb) {
        const __hip_bfloat16* xr = xb + cb * 64 + ch8 * 8;
        gc0 = *(const shortx8*)(xr + (size_t)mi0 * 256);
        gc1 = *(const shortx8*)(xr + (size_t)mi1 * 256);
        gc2 = *(const shortx8*)(xr + (size_t)mi2 * 256);
        gc3 = *(const shortx8*)(xr + (size_t)mi3 * 256);
        gw0 = mw0; gw1 = mw1; gw2 = mw2; gw3 = mw3;
    };
    auto gather_store = [&](int buf) {
        shortx8 o;
#pragma unroll
        for (int j = 0; j < 8; ++j)
            o[j] = f2bf(gw0 * bf2f(gc0[j]) + gw1 * bf2f(gc1[j])
                      + gw2 * bf2f(gc2[j]) + gw3 * bf2f(gc3[j]));
        *(shortx8*)&As[buf][aslot] = o;
    };

    __syncthreads();                // meta visible (also drains B0 DMA)
    meta_load(0);
    gather_load(0);                 // corners for step 0
    gather_store(0);                // exposed once (prologue only)
    gather_load(1);                 // corners for step 1 (cb=1, tap 0)

    int swz = ln & 7;               // read-slot XOR key

    for (int kt = 0; kt < 36; ++kt) {
        int cur = kt & 1;
        int nxt = cur ^ 1;
        __syncthreads();            // buf[cur] staged; ALSO drains gc loads
        if (kt + 1 < 36) {
            int ko = (kt + 1) * 64;
#pragma unroll
            for (int h = 0; h < 4; ++h)
                gll16(gB + (size_t)(h * 32) * CK + ko, &Bs[nxt][lof + h * 2048]);
        }
#pragma unroll
        for (int kh = 0; kh < 2; ++kh) {
            int slot = ((kh * 4 + quad) ^ swz) * 8;
            shortx8 af = *(const shortx8*)
                &As[cur][(wm * 16 + ln) * 64 + slot];
            shortx8 bf[4];
#pragma unroll
            for (int nf = 0; nf < 4; ++nf)
                bf[nf] = *(const shortx8*)
                    &Bs[cur][(wn * 64 + nf * 16 + ln) * 64 + slot];
#pragma unroll
            for (int nf = 0; nf < 4; ++nf)
                acc[nf] = __builtin_amdgcn_mfma_f32_16x16x32_bf16(
                    af, bf[nf], acc[nf], 0, 0, 0);
        }
        if (kt + 1 < 36) gather_store(nxt);   // gc drained -> zero-wait consume
        if (kt + 2 < 36) {                    // issue loads for step kt+2
            int k2 = kt + 2;
            if ((k2 & 3) == 0) meta_load(k2 >> 2);
            gather_load(k2 & 3);
        }
    }

    // epilogue (verbatim R13/R14): per-wave LDS transpose
    int bb = mt >> 7;
    int hw0 = (mt & 127) * 32 + wm * 16;
    float* sw = &s_out[w][0];
    int co_l = lane >> 2;
    int seg  = lane & 3;
#pragma unroll
    for (int nf = 0; nf < 4; ++nf) {
        *(floatx4*)&sw[ln * 20 + quad * 4] = acc[nf];
        floatx4 v0 = *(const floatx4*)&sw[co_l * 20 + seg * 4];
        int co = nt * 128 + wn * 64 + nf * 16 + co_l;
        float* orow = out + ((size_t)(bb * COo + co) << 12) + hw0;
        *(floatx4*)&orow[seg * 4] = v0;
    }
}

// ---------------------------------------------------------------------------
extern "C" void kernel_launch(void* const* d_in, const int* in_sizes, int n_in,
                              void* d_out, int out_size, void* d_ws, size_t ws_size,
                              hipStream_t stream)
{
    const float* x     = (const float*)d_in[0];
    const float* resid = (const float*)d_in[1];
    const float* off_w = (const float*)d_in[2];
    const float* off_b = (const float*)d_in[3];
    const float* mod_w = (const float*)d_in[4];
    const float* mod_b = (const float*)d_in[5];
    const float* reg_w = (const float*)d_in[6];
    float* out = (float*)d_out;

    float* ws = (float*)d_ws;
    float* off_buf   = ws + O_OFF;
    float* mask_buf  = ws + O_MASK;
    __hip_bfloat16* Wbf  = (__hip_bfloat16*)(ws + O_WBF);
    __hip_bfloat16* Wpk  = (__hip_bfloat16*)(ws + O_WPK);
    __hip_bfloat16* xT   = (__hip_bfloat16*)(ws + O_XT);
    __hip_bfloat16* resT = (__hip_bfloat16*)(ws + O_RT);

    // fused transpose (2048 blocks) + weight pack (2304 blocks)
    prep_kernel<<<2048 + (CK * COo + 255) / 256, 256, 0, stream>>>(
        x, resid, reg_w, off_w, mod_w, xT, resT, Wbf, Wpk);

    convA2_kernel<<<512, 512, 0, stream>>>(xT, resT, Wpk, off_b, mod_b,
                                           off_buf, mask_buf);

    gemm_fused_kernel<<<512, 256, 0, stream>>>(xT, off_buf, mask_buf, Wbf, out);
}